// Round 1
// baseline (1647.004 us; speedup 1.0000x reference)
//
#include <hip/hip_runtime.h>
#include <cstdint>
#include <cstddef>

#define NB 512
#define NO 32
#define NR 2048
#define ND 256

// ------------------------------------------------------------------
// Kernel 1: S[b, o, r] = sum_d Q[b,o,d] * C[b,r,d]   (fp32 GEMM)
// grid 4096 = (b:512) x (rtile:8, 256 rows each); block 256 threads
// thread (to = t>>5 in 0..7, tr = t&31): computes 4 o's x 8 r's
// LDS: As = full-K query tile [32][256] (stride 260, broadcast reads)
//      Bs = context k-chunk  [256 r][32 k], XOR-swizzled, restaged 8x
// ------------------------------------------------------------------
__global__ __launch_bounds__(256, 2)
void k_scores(const float* __restrict__ Q, const float* __restrict__ C,
              float* __restrict__ S)
{
    __shared__ float As[NO * 260];   // 33.3 KB
    __shared__ float Bs[256 * 32];   // 32 KB

    const int t   = threadIdx.x;
    const int bid = blockIdx.x;
    const int b   = bid >> 3;
    const int rt  = bid & 7;

    const float* qb = Q + (size_t)b * NO * ND;
    const float* cb = C + (size_t)b * NR * ND + (size_t)rt * 256 * ND;

    // ---- stage As (full K=256), coalesced float4 ----
#pragma unroll
    for (int i = 0; i < 8; ++i) {
        int f  = t + 256 * i;        // float4 index into 32x256
        int o  = f >> 6;             // 64 float4 per o-row
        int k4 = f & 63;
        float4 v = ((const float4*)qb)[f];
        *(float4*)&As[o * 260 + k4 * 4] = v;
    }

    const int base_row = t >> 3;     // 0..31
    const int sub      = t & 7;      // float4 slot within 32-float row chunk

    // prefetch context k-chunk 0 into registers (full 128B lines per row)
    float4 pf[8];
#pragma unroll
    for (int i = 0; i < 8; ++i)
        pf[i] = *(const float4*)(cb + (size_t)(base_row + 32 * i) * ND + sub * 4);

    const int to  = t >> 5;          // 0..7  -> o = to*4 + i
    const int tr  = t & 31;          // 0..31 -> r = tr*8 + j
    const int key = (tr & 7) << 2;   // xor-swizzle key for b-frag reads

    float acc[4][8];
#pragma unroll
    for (int i = 0; i < 4; ++i)
#pragma unroll
        for (int j = 0; j < 8; ++j) acc[i][j] = 0.f;

    for (int kc = 0; kc < 8; ++kc) {
        __syncthreads();             // prev compute done (iter0: covers As too)
#pragma unroll
        for (int i = 0; i < 8; ++i) {
            int row = base_row + 32 * i;
            int sw  = ((row >> 3) & 7) << 2;
            *(float4*)&Bs[row * 32 + ((sub * 4) ^ sw)] = pf[i];
        }
        __syncthreads();

        if (kc < 7) {                // prefetch next chunk under compute
            int k0n = (kc + 1) * 32;
#pragma unroll
            for (int i = 0; i < 8; ++i)
                pf[i] = *(const float4*)(cb + (size_t)(base_row + 32 * i) * ND
                                            + k0n + sub * 4);
        }

        const int k0 = kc * 32;
#pragma unroll
        for (int kk = 0; kk < 32; kk += 4) {
            float4 a[4], bf[8];
#pragma unroll
            for (int i = 0; i < 4; ++i)
                a[i] = *(const float4*)&As[(to * 4 + i) * 260 + k0 + kk];
            const int sw = kk ^ key;
#pragma unroll
            for (int j = 0; j < 8; ++j)
                bf[j] = *(const float4*)&Bs[(tr * 8 + j) * 32 + sw];
#pragma unroll
            for (int i = 0; i < 4; ++i)
#pragma unroll
                for (int j = 0; j < 8; ++j) {
                    acc[i][j] += a[i].x * bf[j].x;
                    acc[i][j] += a[i].y * bf[j].y;
                    acc[i][j] += a[i].z * bf[j].z;
                    acc[i][j] += a[i].w * bf[j].w;
                }
        }
    }

    // ---- store scores into d_out (k2 rewrites in place) ----
#pragma unroll
    for (int i = 0; i < 4; ++i) {
        int o = to * 4 + i;
        float* p = S + (size_t)(b * NO + o) * NR + rt * 256 + tr * 8;
        *(float4*)p       = make_float4(acc[i][0], acc[i][1], acc[i][2], acc[i][3]);
        *(float4*)(p + 4) = make_float4(acc[i][4], acc[i][5], acc[i][6], acc[i][7]);
    }
}

// ------------------------------------------------------------------
// Kernel 2: in-place sparsemax over each row of 2048.
// One wave (64 lanes) per row, 4 rows per 256-thread block. No barriers.
// Michelot fixed-point: tau <- (sum_{z>tau} z - 1)/count, from tau=max-1;
// monotone increasing, finite convergence to the exact sort-based tau.
// ------------------------------------------------------------------
__global__ __launch_bounds__(256)
void k_sparsemax(float* __restrict__ S)
{
    const int lane = threadIdx.x & 63;
    const int wv   = threadIdx.x >> 6;
    const size_t row = (size_t)blockIdx.x * 4 + wv;   // < 16384
    float4* p = (float4*)(S + row * NR);              // 512 float4 per row

    float4 v[8];
#pragma unroll
    for (int i = 0; i < 8; ++i) v[i] = p[lane + 64 * i];

    float m = -1e30f;
#pragma unroll
    for (int i = 0; i < 8; ++i)
        m = fmaxf(m, fmaxf(fmaxf(v[i].x, v[i].y), fmaxf(v[i].z, v[i].w)));
#pragma unroll
    for (int d = 1; d < 64; d <<= 1) m = fmaxf(m, __shfl_xor(m, d));

    float tau = m - 1.0f;
    for (int it = 0; it < 40; ++it) {
        float s = 0.f, c = 0.f;
#pragma unroll
        for (int i = 0; i < 8; ++i) {
            if (v[i].x > tau) { s += v[i].x; c += 1.f; }
            if (v[i].y > tau) { s += v[i].y; c += 1.f; }
            if (v[i].z > tau) { s += v[i].z; c += 1.f; }
            if (v[i].w > tau) { s += v[i].w; c += 1.f; }
        }
#pragma unroll
        for (int d = 1; d < 64; d <<= 1) {
            s += __shfl_xor(s, d);
            c += __shfl_xor(c, d);
        }
        float tn = (s - 1.0f) / c;   // c >= 1 always (max element in support)
        if (tn <= tau) break;        // fixed point reached -> exact tau
        tau = tn;
    }

#pragma unroll
    for (int i = 0; i < 8; ++i) {
        float4 w;
        w.x = fmaxf(v[i].x - tau, 0.f);
        w.y = fmaxf(v[i].y - tau, 0.f);
        w.z = fmaxf(v[i].z - tau, 0.f);
        w.w = fmaxf(v[i].w - tau, 0.f);
        p[lane + 64 * i] = w;
    }
}

extern "C" void kernel_launch(void* const* d_in, const int* in_sizes, int n_in,
                              void* d_out, int out_size, void* d_ws, size_t ws_size,
                              hipStream_t stream) {
    (void)in_sizes; (void)n_in; (void)d_ws; (void)ws_size; (void)out_size;
    const float* Q = (const float*)d_in[0];   // [512, 32, 256]
    const float* C = (const float*)d_in[1];   // [512, 2048, 256]
    float* out = (float*)d_out;               // [16384, 2048]

    hipLaunchKernelGGL(k_scores,    dim3(4096), dim3(256), 0, stream, Q, C, out);
    hipLaunchKernelGGL(k_sparsemax, dim3(4096), dim3(256), 0, stream, out);
}